// Round 22
// baseline (229.050 us; speedup 1.0000x reference)
//
#include <hip/hip_runtime.h>

#define NT 512   // 8 independent waves per block; no barriers anywhere

typedef float v2f __attribute__((ext_vector_type(2)));
typedef float f4u __attribute__((ext_vector_type(4), aligned(4)));
typedef float f4a __attribute__((ext_vector_type(4), aligned(16)));

// Gaussian(sigma=1.5, 11 taps), normalized; 0 outside [0,10]
__device__ __forceinline__ constexpr float Wj(int j) {
    return (j < 0 || j > 10) ? 0.f :
           (j == 0 || j == 10) ? 0.00102838f :
           (j == 1 || j == 9)  ? 0.00759878f :
           (j == 2 || j == 8)  ? 0.03600077f :
           (j == 3 || j == 7)  ? 0.10936069f :
           (j == 4 || j == 6)  ? 0.21300553f : 0.26601172f;
}

// Sliding-window MS-SSIM level kernel, depth-2 pipeline, slim body
// (r14/r20/r21-verified math; this round only changes block size 256->512).
__global__ __attribute__((amdgpu_flat_work_group_size(NT, NT), amdgpu_waves_per_eu(2, 8)))
void msssim_slide(
    const float* __restrict__ x1, const float* __restrict__ x2, int strideIn,
    const float* __restrict__ ex1, const float* __restrict__ ex2,
    float* __restrict__ p1, float* __restrict__ p2, int strideOut,
    float* __restrict__ accCS, float* __restrict__ accSSIM,
    int H, int W, int nStrips, int chunksY, int chunkRows)
{
    const int t = threadIdx.x;
    const int lane = t & 63;

    // ---- bijective XCD swizzle (gridDim.x always a multiple of 8) ----
    const int cpx = gridDim.x >> 3;
    const int lb = (blockIdx.x & 7) * cpx + (blockIdx.x >> 3);
    const int wid = lb * (NT / 64) + (t >> 6);

    const int perImg = nStrips * chunksY;
    const int img = wid / perImg;
    const int rem = wid - img * perImg;
    const int strip = rem / chunksY;           // vertical-first within image
    const int chunk = rem - strip * chunksY;
    const int cc = strip * 64 + lane;          // my output column
    const int r0 = chunk * chunkRows;          // first output row (EVEN)
    const int hEnd = r0 + chunkRows + 5;       // last input row + 1
    const bool laneValid = (cc < W);
    const bool doPool = (p1 != nullptr);

    // ---- per-wave base-pointer/stride selection (uniform, setup-only) ----
    const float* __restrict__ base1;
    const float* __restrict__ base2;
    int sIn;
    if (ex1 != nullptr && (strip == 0 || strip == nStrips - 1)) {
        const int side = (strip != 0);
        const size_t eoff = ((size_t)(side * 48 + img)) * H * 80;
        const int adj = side ? -(W - 72) : 8;   // col c -> band index
        base1 = ex1 + eoff + adj;
        base2 = ex2 + eoff + adj;
        sIn = 80;
    } else {
        base1 = x1 + (size_t)img * H * strideIn;
        base2 = x2 + (size_t)img * H * strideIn;
        sIn = strideIn;
    }

    const size_t imgOut = doPool ? (size_t)img * (H >> 1) * strideOut : 0;
    float* __restrict__ q1 = doPool ? (p1 + imgOut) : nullptr;
    float* __restrict__ q2 = doPool ? (p2 + imgOut) : nullptr;

    float nA1[12], nA2[12], nB1[12], nB2[12];  // ping-pong row windows
    v2f psd[11], psq[11];       // pending V-outputs ring (assign-first lifecycle)
    float prs1 = 0.f, prs2 = 0.f;  // pool row-pair partial sums
    float cs_s = 0.f, ssim_s = 0.f;

    auto loadRow = [&](int h, float (&d1)[12], float (&d2)[12]) {
        if (h < 0 || h >= H || !laneValid) return;   // zero-pad rows / idle lanes
        const float* __restrict__ r1 = base1 + (size_t)h * sIn + (cc - 5);
        const float* __restrict__ r2 = base2 + (size_t)h * sIn + (cc - 5);
        const f4u* a4 = reinterpret_cast<const f4u*>(r1);
        const f4u* b4 = reinterpret_cast<const f4u*>(r2);
        f4u A0 = a4[0], A1 = a4[1], A2 = a4[2];
        f4u B0 = b4[0], B1 = b4[1], B2 = b4[2];
#pragma unroll
        for (int j = 0; j < 4; ++j) { d1[j] = A0[j]; d1[4 + j] = A1[j]; d1[8 + j] = A2[j]; }
#pragma unroll
        for (int j = 0; j < 4; ++j) { d2[j] = B0[j]; d2[4 + j] = B1[j]; d2[8 + j] = B2[j]; }
    };

    // prologue: rows r0-5 (buffer A) and r0-4 (buffer B) in flight
    loadRow(r0 - 5, nA1, nA2);
    loadRow(r0 - 4, nB1, nB2);

    const float C1 = 0.0001f, C2 = 0.0009f;

    // hb = r0-5 is ODD (r0 even) => pp even <-> h odd, pp odd <-> h even
    for (int hb = r0 - 5; hb < hEnd; hb += 22) {
#pragma unroll
        for (int pp = 0; pp < 22; ++pp) {
            const int h = hb + pp;
            if (h < hEnd) {
                const int p = pp % 11;                       // ring phase
                float (&x1w)[12] = (pp & 1) ? nB1 : nA1;     // compile-time parity
                float (&x2w)[12] = (pp & 1) ? nB2 : nA2;

                // ---- 1. consume buffered row h: H-filter 4 moments ----
                v2f acc_sd = (v2f){0.f, 0.f}, acc_sq = (v2f){0.f, 0.f};
                if (h >= 0 && h < H) {
                    if (doPool && h >= r0 && h < r0 + chunkRows) {
                        if ((pp & 1) == 1) {                 // h EVEN: save pair
                            prs1 = x1w[5] + x1w[6];
                            prs2 = x2w[5] + x2w[6];
                        } else if (!(lane & 1) && laneValid) {  // h ODD: write pooled
                            size_t po = (size_t)(h >> 1) * strideOut + (cc >> 1);
                            q1[po] = 0.25f * (prs1 + x1w[5] + x1w[6]);
                            q2[po] = 0.25f * (prs2 + x2w[5] + x2w[6]);
                        }
                    }
#pragma unroll
                    for (int j = 0; j < 11; ++j) {
                        // {s, d} = {x1+x2, x1-x2} in ONE packed fma
                        v2f xx1 = {x1w[j], x1w[j]};
                        v2f xx2 = {x2w[j], x2w[j]};
                        v2f sd = __builtin_elementwise_fma((v2f){1.f, -1.f}, xx2, xx1);
                        v2f w2 = {Wj(j), Wj(j)};
                        acc_sd = __builtin_elementwise_fma(w2, sd, acc_sd);
                        acc_sq = __builtin_elementwise_fma(w2, sd * sd, acc_sq);
                    }
                }
                // ---- 2. issue row h+2 into the just-consumed buffer ----
                if (h + 2 < hEnd) loadRow(h + 2, x1w, x2w);
                // ---- 3. V-ring update: row h feeds outputs h-5 .. h+5 ----
#pragma unroll
                for (int k = 0; k < 11; ++k) {
                    const int slot = (p + 5 - k + 11) % 11;
                    v2f w2 = {Wj(k), Wj(k)};
                    if (k == 0) {
                        psd[slot] = w2 * acc_sd;
                        psq[slot] = w2 * acc_sq;
                    } else {
                        psd[slot] = __builtin_elementwise_fma(w2, acc_sd, psd[slot]);
                        psq[slot] = __builtin_elementwise_fma(w2, acc_sq, psq[slot]);
                    }
                }
                // ---- 4. emit completed output row o = h-5 (rcp-based) ----
                if (h - 5 >= r0) {
                    const int es = (p + 6) % 11;
                    v2f m2 = psd[es] * psd[es];      // {Sm^2, Dm^2}
                    v2f t1 = psq[es] - m2;           // {SS-Sm^2, DD-Dm^2}
                    float num_cs = 0.5f * (t1.x - t1.y) + C2;
                    float den_cs = 0.5f * (t1.x + t1.y) + C2;
                    float num_ss = 0.5f * (m2.x - m2.y) + C1;
                    float den_ss = 0.5f * (m2.x + m2.y) + C1;
                    float cs = num_cs * __builtin_amdgcn_rcpf(den_cs);
                    float ss = num_ss * cs * __builtin_amdgcn_rcpf(den_ss);
                    if (laneValid) { cs_s += cs; ssim_s += ss; }
                }
            }
        }
    }

    // ---- wave reduction -> 2 atomics per wave ----
#pragma unroll
    for (int off = 32; off > 0; off >>= 1) {
        cs_s += __shfl_down(cs_s, off);
        ssim_s += __shfl_down(ssim_s, off);
    }
    if (lane == 0) {
        atomicAdd(&accCS[img], cs_s);
        atomicAdd(&accSSIM[img], ssim_s);
    }
}

// Build the two 80-col L0 edge bands per image, both inputs:
// e[side][img][row][80]; side 0 = cols -8..71 (left, -8..-1 zero),
// side 1 = cols 440..519 (right, 512..519 zero). One thread per f4.
__global__ void pad_edges_kernel(const float* __restrict__ s1, const float* __restrict__ s2,
                                 float* __restrict__ e1, float* __restrict__ e2) {
    const int PER = 2 * 48 * 512 * 20;               // f4 chunks per input
    int idx = blockIdx.x * blockDim.x + threadIdx.x; // [0, 2*PER)
    int which = idx >= PER;
    int r = which ? idx - PER : idx;
    int c4 = r % 20; r /= 20;
    int row = r % 512; r /= 512;
    int img = r % 48;
    int side = r / 48;
    const float* __restrict__ src = which ? s2 : s1;
    float* __restrict__ dst = (which ? e2 : e1) +
        (((size_t)(side * 48 + img) * 512 + row) * 80) + c4 * 4;
    int colBase = (side ? 440 : -8) + c4 * 4;
    f4a v = {0.f, 0.f, 0.f, 0.f};
    if (side == 0 ? (c4 >= 2) : (c4 < 18))
        v = *(const f4a*)(src + ((size_t)img * 512 + row) * 512 + colBase);
    *(f4a*)dst = v;
}

// Zero the 8-col left/right halos of the padded level-1..4 arrays
__global__ void halo_zero_kernel(float* __restrict__ w1_1, float* __restrict__ w2_1,
                                 float* __restrict__ w1_2, float* __restrict__ w2_2,
                                 float* __restrict__ w1_3, float* __restrict__ w2_3,
                                 float* __restrict__ w1_4, float* __restrict__ w2_4) {
    int idx = blockIdx.x * blockDim.x + threadIdx.x;   // [0, 2*23040)
    if (idx >= 2 * 23040) return;
    int which = idx >= 23040;
    int r = which ? idx - 23040 : idx;
    float* base;
    int stride, Wl;
    if (r < 12288)      { base = which ? w2_1 : w1_1; stride = 272; Wl = 256; }
    else if (r < 18432) { base = which ? w2_2 : w1_2; stride = 144; Wl = 128; r -= 12288; }
    else if (r < 21504) { base = which ? w2_3 : w1_3; stride = 80;  Wl = 64;  r -= 18432; }
    else                { base = which ? w2_4 : w1_4; stride = 48;  Wl = 32;  r -= 21504; }
    float* row = base + (size_t)r * stride;
    f4u z = {0.f, 0.f, 0.f, 0.f};
    *(f4u*)(row - 8) = z;
    *(f4u*)(row - 4) = z;
    *(f4u*)(row + Wl) = z;
    *(f4u*)(row + Wl + 4) = z;
}

// acc layout: CS sums at acc[l*48 + img]; SSIM sums at acc[256 + l*48 + img]
__global__ void finalize_kernel(const float* __restrict__ acc, float* __restrict__ out) {
    __shared__ float vals[16];
    int t = threadIdx.x;
    if (t < 16) {
        const float w[5] = {0.0448f, 0.2856f, 0.3001f, 0.2363f, 0.1333f};
        float v = 1.f;
#pragma unroll
        for (int l = 0; l < 5; ++l) {
            int Hl = 512 >> l;
            float denom = 3.f * (float)Hl * (float)Hl;
            const float* src = (l < 4) ? (acc + l * 48) : (acc + 256 + l * 48);
            float m = src[3 * t] + src[3 * t + 1] + src[3 * t + 2];
            m = m / denom;
            m = fmaxf(m, 0.f);
            v *= powf(m, w[l]);
        }
        vals[t] = v;
    }
    __syncthreads();
    if (t == 0) {
        float s = 0.f;
        for (int i = 0; i < 16; ++i) s += vals[i];
        out[0] = s / 16.f;
    }
}

extern "C" void kernel_launch(void* const* d_in, const int* in_sizes, int n_in,
                              void* d_out, int out_size, void* d_ws, size_t ws_size,
                              hipStream_t stream) {
    const float* img1 = (const float*)d_in[0];
    const float* img2 = (const float*)d_in[1];
    float* out = (float*)d_out;
    float* ws = (float*)d_ws;

    float* acc = ws;
    size_t off = 512;

    // padded level-1..4 arrays: stride Wl+16, pointer offset +8
    float* a1[5];
    float* a2[5];
    int strideL[5];
    strideL[0] = 512;
    for (int l = 1; l < 5; ++l) {
        int Hl = 512 >> l;
        strideL[l] = Hl + 16;
        a1[l] = ws + off + 8; off += (size_t)48 * Hl * strideL[l];
    }
    for (int l = 1; l < 5; ++l) {
        int Hl = 512 >> l;
        a2[l] = ws + off + 8; off += (size_t)48 * Hl * strideL[l];
    }

    // L0 edge bands: 2 inputs x [2 sides][48][512][80] floats
    float* e1 = ws + off; off += (size_t)2 * 48 * 512 * 80;
    float* e2 = ws + off; off += (size_t)2 * 48 * 512 * 80;

    hipMemsetAsync(acc, 0, 512 * sizeof(float), stream);
    halo_zero_kernel<<<(2 * 23040 + 255) / 256, 256, 0, stream>>>(
        a1[1], a2[1], a1[2], a2[2], a1[3], a2[3], a1[4], a2[4]);
    pad_edges_kernel<<<(2 * 2 * 48 * 512 * 20) / 256, 256, 0, stream>>>(
        img1, img2, e1, e2);

    // L0: 8 strips, chunkRows 32 -> 6144 waves, 768 blocks (512-thread)
    msssim_slide<<<768, NT, 0, stream>>>(
        img1, img2, 512, e1, e2, a1[1], a2[1], strideL[1],
        acc, acc + 256, 512, 512, 8, 16, 32);
    // L1: 4 strips, crows 16 -> 3072 waves, 384 blocks
    msssim_slide<<<384, NT, 0, stream>>>(
        a1[1], a2[1], strideL[1], nullptr, nullptr, a1[2], a2[2], strideL[2],
        acc + 48, acc + 256 + 48, 256, 256, 4, 16, 16);
    // L2: 2 strips, crows 8 -> 1536 waves, 192 blocks
    msssim_slide<<<192, NT, 0, stream>>>(
        a1[2], a2[2], strideL[2], nullptr, nullptr, a1[3], a2[3], strideL[3],
        acc + 96, acc + 256 + 96, 128, 128, 2, 16, 8);
    // L3: 1 strip, crows 8 -> 384 waves, 48 blocks
    msssim_slide<<<48, NT, 0, stream>>>(
        a1[3], a2[3], strideL[3], nullptr, nullptr, a1[4], a2[4], strideL[4],
        acc + 144, acc + 256 + 144, 64, 64, 1, 8, 8);
    // L4: 1 strip, crows 4 -> 192 waves, 24 blocks
    msssim_slide<<<24, NT, 0, stream>>>(
        a1[4], a2[4], strideL[4], nullptr, nullptr, nullptr, nullptr, 0,
        acc + 192, acc + 256 + 192, 32, 32, 1, 4, 8);

    finalize_kernel<<<1, 64, 0, stream>>>(acc, out);
}

// Round 23
// 190.900 us; speedup vs baseline: 1.1998x; 1.1998x over previous
//
#include <hip/hip_runtime.h>

#define NT 256   // 4 independent waves per block; no barriers anywhere

typedef float v2f __attribute__((ext_vector_type(2)));
typedef float f4u __attribute__((ext_vector_type(4), aligned(4)));
typedef float f4a __attribute__((ext_vector_type(4), aligned(16)));

// Gaussian(sigma=1.5, 11 taps), normalized; 0 outside [0,10]
__device__ __forceinline__ constexpr float Wj(int j) {
    return (j < 0 || j > 10) ? 0.f :
           (j == 0 || j == 10) ? 0.00102838f :
           (j == 1 || j == 9)  ? 0.00759878f :
           (j == 2 || j == 8)  ? 0.03600077f :
           (j == 3 || j == 7)  ? 0.10936069f :
           (j == 4 || j == 6)  ? 0.21300553f : 0.26601172f;
}

// Sliding-window MS-SSIM level kernel, depth-2 pipeline, slim body
// (r14/r20/r21-verified math; byte-identical to the round-21 best kernel).
__global__ __attribute__((amdgpu_flat_work_group_size(NT, NT), amdgpu_waves_per_eu(2, 4)))
void msssim_slide(
    const float* __restrict__ x1, const float* __restrict__ x2, int strideIn,
    const float* __restrict__ ex1, const float* __restrict__ ex2,
    float* __restrict__ p1, float* __restrict__ p2, int strideOut,
    float* __restrict__ accCS, float* __restrict__ accSSIM,
    int H, int W, int nStrips, int chunksY, int chunkRows)
{
    const int t = threadIdx.x;
    const int lane = t & 63;

    // ---- bijective XCD swizzle (gridDim.x always a multiple of 8) ----
    const int cpx = gridDim.x >> 3;
    const int lb = (blockIdx.x & 7) * cpx + (blockIdx.x >> 3);
    const int wid = lb * (NT / 64) + (t >> 6);

    const int perImg = nStrips * chunksY;
    const int img = wid / perImg;
    const int rem = wid - img * perImg;
    const int strip = rem / chunksY;           // vertical-first within image
    const int chunk = rem - strip * chunksY;
    const int cc = strip * 64 + lane;          // my output column
    const int r0 = chunk * chunkRows;          // first output row (EVEN)
    const int hEnd = r0 + chunkRows + 5;       // last input row + 1
    const bool laneValid = (cc < W);
    const bool doPool = (p1 != nullptr);

    // ---- per-wave base-pointer/stride selection (uniform, setup-only) ----
    const float* __restrict__ base1;
    const float* __restrict__ base2;
    int sIn;
    if (ex1 != nullptr && (strip == 0 || strip == nStrips - 1)) {
        const int side = (strip != 0);
        const size_t eoff = ((size_t)(side * 48 + img)) * H * 80;
        const int adj = side ? -(W - 72) : 8;   // col c -> band index
        base1 = ex1 + eoff + adj;
        base2 = ex2 + eoff + adj;
        sIn = 80;
    } else {
        base1 = x1 + (size_t)img * H * strideIn;
        base2 = x2 + (size_t)img * H * strideIn;
        sIn = strideIn;
    }

    const size_t imgOut = doPool ? (size_t)img * (H >> 1) * strideOut : 0;
    float* __restrict__ q1 = doPool ? (p1 + imgOut) : nullptr;
    float* __restrict__ q2 = doPool ? (p2 + imgOut) : nullptr;

    float nA1[12], nA2[12], nB1[12], nB2[12];  // ping-pong row windows
    v2f psd[11], psq[11];       // pending V-outputs ring (assign-first lifecycle)
    float prs1 = 0.f, prs2 = 0.f;  // pool row-pair partial sums
    float cs_s = 0.f, ssim_s = 0.f;

    auto loadRow = [&](int h, float (&d1)[12], float (&d2)[12]) {
        if (h < 0 || h >= H || !laneValid) return;   // zero-pad rows / idle lanes
        const float* __restrict__ r1 = base1 + (size_t)h * sIn + (cc - 5);
        const float* __restrict__ r2 = base2 + (size_t)h * sIn + (cc - 5);
        const f4u* a4 = reinterpret_cast<const f4u*>(r1);
        const f4u* b4 = reinterpret_cast<const f4u*>(r2);
        f4u A0 = a4[0], A1 = a4[1], A2 = a4[2];
        f4u B0 = b4[0], B1 = b4[1], B2 = b4[2];
#pragma unroll
        for (int j = 0; j < 4; ++j) { d1[j] = A0[j]; d1[4 + j] = A1[j]; d1[8 + j] = A2[j]; }
#pragma unroll
        for (int j = 0; j < 4; ++j) { d2[j] = B0[j]; d2[4 + j] = B1[j]; d2[8 + j] = B2[j]; }
    };

    // prologue: rows r0-5 (buffer A) and r0-4 (buffer B) in flight
    loadRow(r0 - 5, nA1, nA2);
    loadRow(r0 - 4, nB1, nB2);

    const float C1 = 0.0001f, C2 = 0.0009f;

    // hb = r0-5 is ODD (r0 even) => pp even <-> h odd, pp odd <-> h even
    for (int hb = r0 - 5; hb < hEnd; hb += 22) {
#pragma unroll
        for (int pp = 0; pp < 22; ++pp) {
            const int h = hb + pp;
            if (h < hEnd) {
                const int p = pp % 11;                       // ring phase
                float (&x1w)[12] = (pp & 1) ? nB1 : nA1;     // compile-time parity
                float (&x2w)[12] = (pp & 1) ? nB2 : nA2;

                // ---- 1. consume buffered row h: H-filter 4 moments ----
                v2f acc_sd = (v2f){0.f, 0.f}, acc_sq = (v2f){0.f, 0.f};
                if (h >= 0 && h < H) {
                    if (doPool && h >= r0 && h < r0 + chunkRows) {
                        if ((pp & 1) == 1) {                 // h EVEN: save pair
                            prs1 = x1w[5] + x1w[6];
                            prs2 = x2w[5] + x2w[6];
                        } else if (!(lane & 1) && laneValid) {  // h ODD: write pooled
                            size_t po = (size_t)(h >> 1) * strideOut + (cc >> 1);
                            q1[po] = 0.25f * (prs1 + x1w[5] + x1w[6]);
                            q2[po] = 0.25f * (prs2 + x2w[5] + x2w[6]);
                        }
                    }
#pragma unroll
                    for (int j = 0; j < 11; ++j) {
                        // {s, d} = {x1+x2, x1-x2} in ONE packed fma
                        v2f xx1 = {x1w[j], x1w[j]};
                        v2f xx2 = {x2w[j], x2w[j]};
                        v2f sd = __builtin_elementwise_fma((v2f){1.f, -1.f}, xx2, xx1);
                        v2f w2 = {Wj(j), Wj(j)};
                        acc_sd = __builtin_elementwise_fma(w2, sd, acc_sd);
                        acc_sq = __builtin_elementwise_fma(w2, sd * sd, acc_sq);
                    }
                }
                // ---- 2. issue row h+2 into the just-consumed buffer ----
                if (h + 2 < hEnd) loadRow(h + 2, x1w, x2w);
                // ---- 3. V-ring update: row h feeds outputs h-5 .. h+5 ----
#pragma unroll
                for (int k = 0; k < 11; ++k) {
                    const int slot = (p + 5 - k + 11) % 11;
                    v2f w2 = {Wj(k), Wj(k)};
                    if (k == 0) {
                        psd[slot] = w2 * acc_sd;
                        psq[slot] = w2 * acc_sq;
                    } else {
                        psd[slot] = __builtin_elementwise_fma(w2, acc_sd, psd[slot]);
                        psq[slot] = __builtin_elementwise_fma(w2, acc_sq, psq[slot]);
                    }
                }
                // ---- 4. emit completed output row o = h-5 (rcp-based) ----
                if (h - 5 >= r0) {
                    const int es = (p + 6) % 11;
                    v2f m2 = psd[es] * psd[es];      // {Sm^2, Dm^2}
                    v2f t1 = psq[es] - m2;           // {SS-Sm^2, DD-Dm^2}
                    float num_cs = 0.5f * (t1.x - t1.y) + C2;
                    float den_cs = 0.5f * (t1.x + t1.y) + C2;
                    float num_ss = 0.5f * (m2.x - m2.y) + C1;
                    float den_ss = 0.5f * (m2.x + m2.y) + C1;
                    float cs = num_cs * __builtin_amdgcn_rcpf(den_cs);
                    float ss = num_ss * cs * __builtin_amdgcn_rcpf(den_ss);
                    if (laneValid) { cs_s += cs; ssim_s += ss; }
                }
            }
        }
    }

    // ---- wave reduction -> 2 atomics per wave ----
#pragma unroll
    for (int off = 32; off > 0; off >>= 1) {
        cs_s += __shfl_down(cs_s, off);
        ssim_s += __shfl_down(ssim_s, off);
    }
    if (lane == 0) {
        atomicAdd(&accCS[img], cs_s);
        atomicAdd(&accSSIM[img], ssim_s);
    }
}

// Fused prep: (a) zero 8-col halos of padded L1-4 arrays; (b) build the two
// 80-col L0 edge bands per image for both inputs.
// idx < 2*23040            -> halo part
// idx >= 2*23040           -> pad part (2 inputs x 2 sides x 48 x 512 x 20 f4)
__global__ void prep_kernel(float* __restrict__ w1_1, float* __restrict__ w2_1,
                            float* __restrict__ w1_2, float* __restrict__ w2_2,
                            float* __restrict__ w1_3, float* __restrict__ w2_3,
                            float* __restrict__ w1_4, float* __restrict__ w2_4,
                            const float* __restrict__ s1, const float* __restrict__ s2,
                            float* __restrict__ e1, float* __restrict__ e2) {
    const int HALO = 2 * 23040;
    const int PER = 2 * 48 * 512 * 20;               // f4 chunks per input
    int idx = blockIdx.x * blockDim.x + threadIdx.x;
    if (idx < HALO) {
        int which = idx >= 23040;
        int r = which ? idx - 23040 : idx;
        float* base;
        int stride, Wl;
        if (r < 12288)      { base = which ? w2_1 : w1_1; stride = 272; Wl = 256; }
        else if (r < 18432) { base = which ? w2_2 : w1_2; stride = 144; Wl = 128; r -= 12288; }
        else if (r < 21504) { base = which ? w2_3 : w1_3; stride = 80;  Wl = 64;  r -= 18432; }
        else                { base = which ? w2_4 : w1_4; stride = 48;  Wl = 32;  r -= 21504; }
        float* row = base + (size_t)r * stride;
        f4u z = {0.f, 0.f, 0.f, 0.f};
        *(f4u*)(row - 8) = z;
        *(f4u*)(row - 4) = z;
        *(f4u*)(row + Wl) = z;
        *(f4u*)(row + Wl + 4) = z;
        return;
    }
    idx -= HALO;
    if (idx >= 2 * PER) return;
    int which = idx >= PER;
    int r = which ? idx - PER : idx;
    int c4 = r % 20; r /= 20;
    int row = r % 512; r /= 512;
    int img = r % 48;
    int side = r / 48;
    const float* __restrict__ src = which ? s2 : s1;
    float* __restrict__ dst = (which ? e2 : e1) +
        (((size_t)(side * 48 + img) * 512 + row) * 80) + c4 * 4;
    int colBase = (side ? 440 : -8) + c4 * 4;
    f4a v = {0.f, 0.f, 0.f, 0.f};
    if (side == 0 ? (c4 >= 2) : (c4 < 18))
        v = *(const f4a*)(src + ((size_t)img * 512 + row) * 512 + colBase);
    *(f4a*)dst = v;
}

// acc layout: CS sums at acc[l*48 + img]; SSIM sums at acc[256 + l*48 + img]
__global__ void finalize_kernel(const float* __restrict__ acc, float* __restrict__ out) {
    __shared__ float vals[16];
    int t = threadIdx.x;
    if (t < 16) {
        const float w[5] = {0.0448f, 0.2856f, 0.3001f, 0.2363f, 0.1333f};
        float v = 1.f;
#pragma unroll
        for (int l = 0; l < 5; ++l) {
            int Hl = 512 >> l;
            float denom = 3.f * (float)Hl * (float)Hl;
            const float* src = (l < 4) ? (acc + l * 48) : (acc + 256 + l * 48);
            float m = src[3 * t] + src[3 * t + 1] + src[3 * t + 2];
            m = m / denom;
            m = fmaxf(m, 0.f);
            v *= powf(m, w[l]);
        }
        vals[t] = v;
    }
    __syncthreads();
    if (t == 0) {
        float s = 0.f;
        for (int i = 0; i < 16; ++i) s += vals[i];
        out[0] = s / 16.f;
    }
}

extern "C" void kernel_launch(void* const* d_in, const int* in_sizes, int n_in,
                              void* d_out, int out_size, void* d_ws, size_t ws_size,
                              hipStream_t stream) {
    const float* img1 = (const float*)d_in[0];
    const float* img2 = (const float*)d_in[1];
    float* out = (float*)d_out;
    float* ws = (float*)d_ws;

    float* acc = ws;
    size_t off = 512;

    // padded level-1..4 arrays: stride Wl+16, pointer offset +8
    float* a1[5];
    float* a2[5];
    int strideL[5];
    strideL[0] = 512;
    for (int l = 1; l < 5; ++l) {
        int Hl = 512 >> l;
        strideL[l] = Hl + 16;
        a1[l] = ws + off + 8; off += (size_t)48 * Hl * strideL[l];
    }
    for (int l = 1; l < 5; ++l) {
        int Hl = 512 >> l;
        a2[l] = ws + off + 8; off += (size_t)48 * Hl * strideL[l];
    }

    // L0 edge bands: 2 inputs x [2 sides][48][512][80] floats
    float* e1 = ws + off; off += (size_t)2 * 48 * 512 * 80;
    float* e2 = ws + off; off += (size_t)2 * 48 * 512 * 80;

    hipMemsetAsync(acc, 0, 512 * sizeof(float), stream);
    {
        int total = 2 * 23040 + 2 * (2 * 48 * 512 * 20);
        prep_kernel<<<(total + 255) / 256, 256, 0, stream>>>(
            a1[1], a2[1], a1[2], a2[2], a1[3], a2[3], a1[4], a2[4],
            img1, img2, e1, e2);
    }

    // L0: 8 strips, chunkRows 32 -> 6144 waves, 1536 blocks
    msssim_slide<<<1536, NT, 0, stream>>>(
        img1, img2, 512, e1, e2, a1[1], a2[1], strideL[1],
        acc, acc + 256, 512, 512, 8, 16, 32);
    // L1: 4 strips, crows 16 -> 3072 waves, 768 blocks
    msssim_slide<<<768, NT, 0, stream>>>(
        a1[1], a2[1], strideL[1], nullptr, nullptr, a1[2], a2[2], strideL[2],
        acc + 48, acc + 256 + 48, 256, 256, 4, 16, 16);
    // L2: 2 strips, crows 8 -> 1536 waves, 384 blocks
    msssim_slide<<<384, NT, 0, stream>>>(
        a1[2], a2[2], strideL[2], nullptr, nullptr, a1[3], a2[3], strideL[3],
        acc + 96, acc + 256 + 96, 128, 128, 2, 16, 8);
    // L3: 1 strip, crows 4 -> 768 waves, 192 blocks
    msssim_slide<<<192, NT, 0, stream>>>(
        a1[3], a2[3], strideL[3], nullptr, nullptr, a1[4], a2[4], strideL[4],
        acc + 144, acc + 256 + 144, 64, 64, 1, 16, 4);
    // L4: 1 strip, crows 4 -> 384 waves, 96 blocks
    msssim_slide<<<96, NT, 0, stream>>>(
        a1[4], a2[4], strideL[4], nullptr, nullptr, nullptr, nullptr, 0,
        acc + 192, acc + 256 + 192, 32, 32, 1, 8, 4);

    finalize_kernel<<<1, 64, 0, stream>>>(acc, out);
}